// Round 4
// baseline (1639.542 us; speedup 1.0000x reference)
//
#include <hip/hip_runtime.h>

// ERNN cell on MI355X. Inputs/outputs are FLOAT32 (per reference; proven by the
// NaN-bit argument: bf16-misreads of f32 data inject exp=0xFF patterns -> NaN,
// observed in R1/R3; true bf16 inputs admit no NaN path in this recurrence).
// Math: P = V2@V + I;  per step t:
//   s = h_cur + h_prev;  pre = s + s@(P^2 - I) + (x[t]@(W@P) + b@P)
//   h_cur = a*(tanh(pre) - h_prev) + (1-a)*h_cur   (K iters, K=1)
// Identity split keeps the MFMA operand (E = P^2 - I) small -> bf16 rounding harmless.
// h state stays f32 in registers; only bf16 's' staging round-trips LDS.
// Workspace use: 449 KB only.

#define HID   256
#define NF    128
#define SEQ   1024
#define SSTR  264    // s LDS row stride in bf16 elems (pad 8)

typedef __bf16 bf16_t;
typedef __bf16 bf16x8 __attribute__((ext_vector_type(8)));
typedef float  f32x4  __attribute__((ext_vector_type(4)));

__device__ __forceinline__ float fast_tanh(float x) {
    // tanh(x) = 1 - 2/(exp2(2*log2e*x) + 1); v_exp handles +-inf saturation
    float e = __builtin_amdgcn_exp2f(x * 2.8853900817779268f);
    return 1.0f - 2.0f * __builtin_amdgcn_rcpf(e + 1.0f);
}

// ---------- k0: P = V2@V + I (f32) ----------
__global__ void k_P(const float* __restrict__ V2, const float* __restrict__ V,
                    float* __restrict__ P) {
    __shared__ float v2row[64];
    int i = blockIdx.x, j = threadIdx.x;
    if (j < 64) v2row[j] = V2[i * 64 + j];
    __syncthreads();
    float s = (i == j) ? 1.0f : 0.0f;
    #pragma unroll 4
    for (int v = 0; v < 64; ++v) s += v2row[v] * V[v * HID + j];
    P[i * HID + j] = s;
}

// ---------- k1: E = bf16(P@P - I) ----------
__global__ void k_E(const float* __restrict__ P, bf16_t* __restrict__ E) {
    __shared__ float prow[HID];
    int i = blockIdx.x, j = threadIdx.x;
    prow[j] = P[i * HID + j];
    __syncthreads();
    float s = (i == j) ? -1.0f : 0.0f;
    #pragma unroll 4
    for (int k = 0; k < HID; ++k) s += prow[k] * P[k * HID + j];
    E[i * HID + j] = (bf16_t)s;
}

// ---------- k2: WP = bf16(W@P), bP = b@P (f32) ----------
__global__ void k_WP(const float* __restrict__ W, const float* __restrict__ b,
                     const float* __restrict__ P,
                     bf16_t* __restrict__ WP, float* __restrict__ bP) {
    __shared__ float row[HID];
    int i = blockIdx.x, j = threadIdx.x;
    if (i < NF) {
        row[j] = W[i * HID + j];
        __syncthreads();
        float s = 0.f;
        #pragma unroll 4
        for (int k = 0; k < HID; ++k) s += row[k] * P[k * HID + j];
        WP[i * HID + j] = (bf16_t)s;
    } else {
        row[j] = b[j];
        __syncthreads();
        float s = 0.f;
        #pragma unroll 4
        for (int k = 0; k < HID; ++k) s += row[k] * P[k * HID + j];
        bP[j] = s;
    }
}

// ---------- k3: sequential scan, 16 WGs (16 batch rows each), E+WP in VGPRs ----------
__global__ __launch_bounds__(256, 1) void k_scan(const float* __restrict__ h_in,
                                                 const float* __restrict__ alpha,
                                                 const int* __restrict__ Kp,
                                                 const bf16_t* __restrict__ E,
                                                 const bf16_t* __restrict__ WP,
                                                 const float* __restrict__ bP,
                                                 const float* __restrict__ x,
                                                 float* __restrict__ out) {
    __shared__ bf16_t S[2][16 * SSTR];   // staged s = h_cur + h_prev (bf16, dbuf)
    int g = blockIdx.x;
    int tid = threadIdx.x;
    int lane = tid & 63, w = tid >> 6, quad = lane >> 4, m = lane & 15;
    int colbase = w * 64 + m;

    // persistent B fragments: wave w owns cols [64w, 64w+64)
    // B-layout of mfma_16x16x32: lane(n=lane&15, q=lane>>4) holds B[k=32kt+8q+j][n]
    bf16x8 Ef[32];                        // E (256xK): index c*8 + kt, kt 0..7
    bf16x8 Wf[16];                        // WP (128xK): index c*4 + kt, kt 0..3
    float bPv[4];
    #pragma unroll
    for (int c = 0; c < 4; ++c) {
        int col = colbase + c * 16;
        bPv[c] = bP[col];
        #pragma unroll
        for (int kt = 0; kt < 8; ++kt) {
            bf16x8 f;
            #pragma unroll
            for (int j = 0; j < 8; ++j)
                f[j] = E[(kt * 32 + quad * 8 + j) * HID + col];
            Ef[c * 8 + kt] = f;
        }
        #pragma unroll
        for (int kt = 0; kt < 4; ++kt) {
            bf16x8 f;
            #pragma unroll
            for (int j = 0; j < 8; ++j)
                f[j] = WP[(kt * 32 + quad * 8 + j) * HID + col];
            Wf[c * 4 + kt] = f;
        }
    }

    // h state in registers at this lane's C-layout positions:
    // e = c*4 + r  ->  (row = quad*4 + r, col = colbase + 16c)
    float hp[16], hc[16], sreg[16];
    #pragma unroll
    for (int c = 0; c < 4; ++c)
        #pragma unroll
        for (int r = 0; r < 4; ++r) {
            int e = c * 4 + r;
            int row = quad * 4 + r, col = colbase + c * 16;
            float v = h_in[(g * 16 + row) * HID + col];
            hp[e] = v; hc[e] = v; sreg[e] = 2.0f * v;
            S[0][row * SSTR + col] = (bf16_t)(2.0f * v);
        }
    float a = alpha[0];
    float one_ma = 1.0f - a;
    int K = Kp[0];
    if (K < 1 || K > 64) K = 1;   // defensive vs mis-typed scalar
    __syncthreads();

    // x A-fragments: lane needs x[t, g*16+m, kt*32 + quad*8 + j] (f32 -> bf16)
    const float* xrow = x + ((g * 16 + m) * NF + quad * 8);
    bf16x8 xf[4];
    #pragma unroll
    for (int kt = 0; kt < 4; ++kt) {
        f32x4 xa = *(const f32x4*)(xrow + kt * 32);
        f32x4 xb = *(const f32x4*)(xrow + kt * 32 + 4);
        bf16x8 f;
        #pragma unroll
        for (int j = 0; j < 4; ++j) { f[j] = (bf16_t)xa[j]; f[4 + j] = (bf16_t)xb[j]; }
        xf[kt] = f;
    }

    int p = 0;
    for (int t = 0; t < SEQ; ++t) {
        int tn = (t + 1 < SEQ) ? t + 1 : t;
        const float* xn = xrow + tn * (256 * NF);
        bf16x8 xnf[4];                     // prefetch next step's x fragment
        #pragma unroll
        for (int kt = 0; kt < 4; ++kt) {
            f32x4 xa = *(const f32x4*)(xn + kt * 32);
            f32x4 xb = *(const f32x4*)(xn + kt * 32 + 4);
            bf16x8 f;
            #pragma unroll
            for (int j = 0; j < 4; ++j) { f[j] = (bf16_t)xa[j]; f[4 + j] = (bf16_t)xb[j]; }
            xnf[kt] = f;
        }

        // wx part (fixed across K inner iters): bP + x[t]@WP
        f32x4 wxacc[4];
        #pragma unroll
        for (int c = 0; c < 4; ++c) wxacc[c] = (f32x4){bPv[c], bPv[c], bPv[c], bPv[c]};
        #pragma unroll
        for (int kt = 0; kt < 4; ++kt)
            #pragma unroll
            for (int c = 0; c < 4; ++c)
                wxacc[c] = __builtin_amdgcn_mfma_f32_16x16x32_bf16(xf[kt], Wf[c * 4 + kt], wxacc[c], 0, 0, 0);

        for (int k = 0; k < K; ++k) {
            f32x4 acc[4];
            #pragma unroll
            for (int c = 0; c < 4; ++c) acc[c] = wxacc[c];
            const bf16_t* sbase = &S[p][m * SSTR];
            #pragma unroll
            for (int kt = 0; kt < 8; ++kt) {
                bf16x8 af = *(const bf16x8*)(sbase + kt * 32 + quad * 8);
                #pragma unroll
                for (int c = 0; c < 4; ++c)
                    acc[c] = __builtin_amdgcn_mfma_f32_16x16x32_bf16(af, Ef[c * 8 + kt], acc[c], 0, 0, 0);
            }
            bool last = (k == K - 1);
            #pragma unroll
            for (int c = 0; c < 4; ++c) {
                int col = colbase + c * 16;
                #pragma unroll
                for (int r = 0; r < 4; ++r) {
                    int e = c * 4 + r;
                    int row = quad * 4 + r;
                    float pre = acc[c][r] + sreg[e];          // identity part, exact f32
                    float T = fast_tanh(pre);
                    // reference op order: a*(T - oldh) + (1-a)*h_cur
                    float hn = a * (T - hp[e]) + one_ma * hc[e];
                    float sn;
                    if (last) { hp[e] = hn; hc[e] = hn; sn = 2.0f * hn; }
                    else      { hc[e] = hn; sn = hn + hp[e]; }
                    sreg[e] = sn;
                    S[p ^ 1][row * SSTR + col] = (bf16_t)sn;
                }
            }
            p ^= 1;
            __syncthreads();
        }
        #pragma unroll
        for (int kt = 0; kt < 4; ++kt) xf[kt] = xnf[kt];
    }

    #pragma unroll
    for (int c = 0; c < 4; ++c)
        #pragma unroll
        for (int r = 0; r < 4; ++r) {
            int row = quad * 4 + r, col = colbase + c * 16;
            out[(g * 16 + row) * HID + col] = hp[c * 4 + r];   // f32 store
        }
}

extern "C" void kernel_launch(void* const* d_in, const int* in_sizes, int n_in,
                              void* d_out, int out_size, void* d_ws, size_t ws_size,
                              hipStream_t stream) {
    const float* x     = (const float*)d_in[0];
    const float* h     = (const float*)d_in[1];
    const float* W     = (const float*)d_in[2];
    const float* b     = (const float*)d_in[3];
    const float* V     = (const float*)d_in[4];
    const float* V2    = (const float*)d_in[5];
    const float* alpha = (const float*)d_in[6];
    const int*   Kp    = (const int*)d_in[7];

    char* ws = (char*)d_ws;
    float*  P   = (float*)ws;                    // 256 KB
    bf16_t* E   = (bf16_t*)(ws + (256u << 10));  // 128 KB
    bf16_t* WP  = (bf16_t*)(ws + (384u << 10));  // 64 KB
    float*  bP  = (float*)(ws + (448u << 10));   // 1 KB  -> total 449 KB
    (void)ws_size;

    hipLaunchKernelGGL(k_P,    dim3(256), dim3(256), 0, stream, V2, V, P);
    hipLaunchKernelGGL(k_E,    dim3(256), dim3(256), 0, stream, P, E);
    hipLaunchKernelGGL(k_WP,   dim3(129), dim3(256), 0, stream, W, b, P, WP, bP);
    hipLaunchKernelGGL(k_scan, dim3(16),  dim3(256), 0, stream, h, alpha, Kp, E, WP, bP, x, (float*)d_out);
}

// Round 5
// 1157.920 us; speedup vs baseline: 1.4159x; 1.4159x over previous
//
#include <hip/hip_runtime.h>

// ERNN cell on MI355X. Inputs/outputs FLOAT32. Output f32.
// Math: P = V2@V + I;  wxp[t] = x[t]@(W@P) + b@P  (parallel precompute, bf16)
//   per step: s = h_cur + h_prev;  pre = s + s@(P^2 - I) + wxp[t]
//   h_cur = a*(tanh(pre) - h_prev) + (1-a)*h_cur   (K iters, K=1)
// Identity split keeps MFMA operand E = P^2 - I small -> bf16 rounding harmless.
// h stays f32 in registers; bf16 's' staging round-trips LDS (dbuf, 1 barrier/step).
// Scan: 16 WGs x 512 threads (2 waves/SIMD -> epilogue of one wave overlaps MFMA
// of the other). wxp path gated on ws_size; fused fallback = R4's proven kernel.

#define HID   256
#define NF    128
#define SEQ   1024
#define SSTR  264    // s LDS row stride in bf16 elems (pad 8)

typedef __bf16 bf16_t;
typedef __bf16 bf16x8 __attribute__((ext_vector_type(8)));
typedef float  f32x4  __attribute__((ext_vector_type(4)));

__device__ __forceinline__ float fast_tanh(float x) {
    float e = __builtin_amdgcn_exp2f(x * 2.8853900817779268f);
    return 1.0f - 2.0f * __builtin_amdgcn_rcpf(e + 1.0f);
}

// ---------- k0: P = V2@V + I (f32) ----------
__global__ void k_P(const float* __restrict__ V2, const float* __restrict__ V,
                    float* __restrict__ P) {
    __shared__ float v2row[64];
    int i = blockIdx.x, j = threadIdx.x;
    if (j < 64) v2row[j] = V2[i * 64 + j];
    __syncthreads();
    float s = (i == j) ? 1.0f : 0.0f;
    #pragma unroll 4
    for (int v = 0; v < 64; ++v) s += v2row[v] * V[v * HID + j];
    P[i * HID + j] = s;
}

// ---------- k1: E = bf16(P@P - I) ----------
__global__ void k_E(const float* __restrict__ P, bf16_t* __restrict__ E) {
    __shared__ float prow[HID];
    int i = blockIdx.x, j = threadIdx.x;
    prow[j] = P[i * HID + j];
    __syncthreads();
    float s = (i == j) ? -1.0f : 0.0f;
    #pragma unroll 4
    for (int k = 0; k < HID; ++k) s += prow[k] * P[k * HID + j];
    E[i * HID + j] = (bf16_t)s;
}

// ---------- k2: WP = bf16(W@P), bP = b@P (f32) ----------
__global__ void k_WP(const float* __restrict__ W, const float* __restrict__ b,
                     const float* __restrict__ P,
                     bf16_t* __restrict__ WP, float* __restrict__ bP) {
    __shared__ float row[HID];
    int i = blockIdx.x, j = threadIdx.x;
    if (i < NF) {
        row[j] = W[i * HID + j];
        __syncthreads();
        float s = 0.f;
        #pragma unroll 4
        for (int k = 0; k < HID; ++k) s += row[k] * P[k * HID + j];
        WP[i * HID + j] = (bf16_t)s;
    } else {
        row[j] = b[j];
        __syncthreads();
        float s = 0.f;
        #pragma unroll 4
        for (int k = 0; k < HID; ++k) s += row[k] * P[k * HID + j];
        bP[j] = s;
    }
}

// ---------- k3: wxp = bf16(x@WP + bP) in scan-ready layout ----------
// scan lane (wv=tid>>6, lane) reads bf16x8 at ((t*16+g)*512 + tid)*8,
// element e = cc*4 + r = C[quad*4+r][wv*32+16cc+m].
__global__ __launch_bounds__(256) void k_wxp(const float* __restrict__ x,
                                             const bf16_t* __restrict__ WP,
                                             const float* __restrict__ bP,
                                             bf16_t* __restrict__ wxp) {
    int lane = threadIdx.x & 63, w = threadIdx.x >> 6;
    int quad = lane >> 4, m = lane & 15;
    bf16x8 Bf[4][4];
    float bPv[4];
    #pragma unroll
    for (int c = 0; c < 4; ++c) {
        int col = w * 64 + c * 16 + m;
        bPv[c] = bP[col];
        #pragma unroll
        for (int kt = 0; kt < 4; ++kt) {
            bf16x8 f;
            #pragma unroll
            for (int j = 0; j < 8; ++j)
                f[j] = WP[(kt * 32 + quad * 8 + j) * HID + col];
            Bf[c][kt] = f;
        }
    }
    for (int i = 0; i < 8; ++i) {
        int tile = blockIdx.x * 8 + i;          // t*16 + g
        int t = tile >> 4, g = tile & 15;
        const float* xp = x + (((t * 256) + g * 16 + m) * NF + quad * 8);
        f32x4 acc[4];
        #pragma unroll
        for (int c = 0; c < 4; ++c) acc[c] = (f32x4){bPv[c], bPv[c], bPv[c], bPv[c]};
        #pragma unroll
        for (int kt = 0; kt < 4; ++kt) {
            f32x4 xa = *(const f32x4*)(xp + kt * 32);
            f32x4 xb = *(const f32x4*)(xp + kt * 32 + 4);
            bf16x8 a;
            #pragma unroll
            for (int j = 0; j < 4; ++j) { a[j] = (bf16_t)xa[j]; a[4 + j] = (bf16_t)xb[j]; }
            #pragma unroll
            for (int c = 0; c < 4; ++c)
                acc[c] = __builtin_amdgcn_mfma_f32_16x16x32_bf16(a, Bf[c][kt], acc[c], 0, 0, 0);
        }
        // c=0,1 -> scan-wave 2w, elems 0..7; c=2,3 -> scan-wave 2w+1
        bf16x8 lo, hi;
        #pragma unroll
        for (int c = 0; c < 2; ++c)
            #pragma unroll
            for (int r = 0; r < 4; ++r) {
                lo[c * 4 + r] = (bf16_t)acc[c][r];
                hi[c * 4 + r] = (bf16_t)acc[2 + c][r];
            }
        long tb = (long)tile * 512;
        *(bf16x8*)(wxp + (tb + (2 * w) * 64 + lane) * 8)     = lo;
        *(bf16x8*)(wxp + (tb + (2 * w + 1) * 64 + lane) * 8) = hi;
    }
}

// ---------- k4: scan with precomputed wxp; 16 WGs x 512 threads ----------
__global__ __launch_bounds__(512, 2) void k_scan_pre(const float* __restrict__ h_in,
                                                     const float* __restrict__ alpha,
                                                     const int* __restrict__ Kp,
                                                     const bf16_t* __restrict__ E,
                                                     const bf16_t* __restrict__ wxp,
                                                     float* __restrict__ out) {
    __shared__ bf16_t S[2][16 * SSTR];
    int g = blockIdx.x;
    int tid = threadIdx.x;
    int lane = tid & 63, wv = tid >> 6, quad = lane >> 4, m = lane & 15;
    int colbase = wv * 32 + m;

    // B fragments of E for this wave's 32 cols (2 col-tiles x 8 k-tiles)
    bf16x8 Ef[16];
    #pragma unroll
    for (int c = 0; c < 2; ++c) {
        int col = colbase + c * 16;
        #pragma unroll
        for (int kt = 0; kt < 8; ++kt) {
            bf16x8 f;
            #pragma unroll
            for (int j = 0; j < 8; ++j)
                f[j] = E[(kt * 32 + quad * 8 + j) * HID + col];
            Ef[c * 8 + kt] = f;
        }
    }

    float hp[8], hc[8], sreg[8];
    #pragma unroll
    for (int c = 0; c < 2; ++c)
        #pragma unroll
        for (int r = 0; r < 4; ++r) {
            int e = c * 4 + r;
            int row = quad * 4 + r, col = colbase + c * 16;
            float v = h_in[(g * 16 + row) * HID + col];
            hp[e] = v; hc[e] = v; sreg[e] = 2.0f * v;
            S[0][row * SSTR + col] = (bf16_t)(2.0f * v);
        }
    float a = alpha[0];
    float one_ma = 1.0f - a;
    int K = Kp[0];
    if (K < 1 || K > 64) K = 1;
    __syncthreads();

    const bf16x8* wptr = (const bf16x8*)wxp;
    int wbase = g * 512 + tid;                 // vec index; per-t stride 16*512
    bf16x8 wx = wptr[wbase];

    int p = 0;
    for (int t = 0; t < SEQ; ++t) {
        int tn = (t + 1 < SEQ) ? t + 1 : t;
        bf16x8 wxn = wptr[tn * (16 * 512) + wbase];   // prefetch next step

        for (int k = 0; k < K; ++k) {
            f32x4 acc[2];
            #pragma unroll
            for (int c = 0; c < 2; ++c)
                #pragma unroll
                for (int r = 0; r < 4; ++r) acc[c][r] = (float)wx[c * 4 + r];
            const bf16_t* sbase = &S[p][m * SSTR];
            #pragma unroll
            for (int kt = 0; kt < 8; ++kt) {
                bf16x8 af = *(const bf16x8*)(sbase + kt * 32 + quad * 8);
                #pragma unroll
                for (int c = 0; c < 2; ++c)
                    acc[c] = __builtin_amdgcn_mfma_f32_16x16x32_bf16(af, Ef[c * 8 + kt], acc[c], 0, 0, 0);
            }
            bool last = (k == K - 1);
            #pragma unroll
            for (int c = 0; c < 2; ++c) {
                int col = colbase + c * 16;
                #pragma unroll
                for (int r = 0; r < 4; ++r) {
                    int e = c * 4 + r;
                    int row = quad * 4 + r;
                    float pre = acc[c][r] + sreg[e];     // identity part, exact f32
                    float T = fast_tanh(pre);
                    float hn = a * (T - hp[e]) + one_ma * hc[e];
                    float sn;
                    if (last) { hp[e] = hn; hc[e] = hn; sn = 2.0f * hn; }
                    else      { hc[e] = hn; sn = hn + hp[e]; }
                    sreg[e] = sn;
                    S[p ^ 1][row * SSTR + col] = (bf16_t)sn;
                }
            }
            p ^= 1;
            __syncthreads();
        }
        wx = wxn;
    }

    #pragma unroll
    for (int c = 0; c < 2; ++c)
        #pragma unroll
        for (int r = 0; r < 4; ++r) {
            int row = quad * 4 + r, col = colbase + c * 16;
            out[(g * 16 + row) * HID + col] = hp[c * 4 + r];
        }
}

// ---------- fallback: R4's proven fused scan (256 threads) ----------
__global__ __launch_bounds__(256, 1) void k_scan_fused(const float* __restrict__ h_in,
                                                 const float* __restrict__ alpha,
                                                 const int* __restrict__ Kp,
                                                 const bf16_t* __restrict__ E,
                                                 const bf16_t* __restrict__ WP,
                                                 const float* __restrict__ bP,
                                                 const float* __restrict__ x,
                                                 float* __restrict__ out) {
    __shared__ bf16_t S[2][16 * SSTR];
    int g = blockIdx.x;
    int tid = threadIdx.x;
    int lane = tid & 63, w = tid >> 6, quad = lane >> 4, m = lane & 15;
    int colbase = w * 64 + m;
    bf16x8 Ef[32];
    bf16x8 Wf[16];
    float bPv[4];
    #pragma unroll
    for (int c = 0; c < 4; ++c) {
        int col = colbase + c * 16;
        bPv[c] = bP[col];
        #pragma unroll
        for (int kt = 0; kt < 8; ++kt) {
            bf16x8 f;
            #pragma unroll
            for (int j = 0; j < 8; ++j)
                f[j] = E[(kt * 32 + quad * 8 + j) * HID + col];
            Ef[c * 8 + kt] = f;
        }
        #pragma unroll
        for (int kt = 0; kt < 4; ++kt) {
            bf16x8 f;
            #pragma unroll
            for (int j = 0; j < 8; ++j)
                f[j] = WP[(kt * 32 + quad * 8 + j) * HID + col];
            Wf[c * 4 + kt] = f;
        }
    }
    float hp[16], hc[16], sreg[16];
    #pragma unroll
    for (int c = 0; c < 4; ++c)
        #pragma unroll
        for (int r = 0; r < 4; ++r) {
            int e = c * 4 + r;
            int row = quad * 4 + r, col = colbase + c * 16;
            float v = h_in[(g * 16 + row) * HID + col];
            hp[e] = v; hc[e] = v; sreg[e] = 2.0f * v;
            S[0][row * SSTR + col] = (bf16_t)(2.0f * v);
        }
    float a = alpha[0];
    float one_ma = 1.0f - a;
    int K = Kp[0];
    if (K < 1 || K > 64) K = 1;
    __syncthreads();
    const float* xrow = x + ((g * 16 + m) * NF + quad * 8);
    bf16x8 xf[4];
    #pragma unroll
    for (int kt = 0; kt < 4; ++kt) {
        f32x4 xa = *(const f32x4*)(xrow + kt * 32);
        f32x4 xb = *(const f32x4*)(xrow + kt * 32 + 4);
        bf16x8 f;
        #pragma unroll
        for (int j = 0; j < 4; ++j) { f[j] = (bf16_t)xa[j]; f[4 + j] = (bf16_t)xb[j]; }
        xf[kt] = f;
    }
    int p = 0;
    for (int t = 0; t < SEQ; ++t) {
        int tn = (t + 1 < SEQ) ? t + 1 : t;
        const float* xn = xrow + tn * (256 * NF);
        bf16x8 xnf[4];
        #pragma unroll
        for (int kt = 0; kt < 4; ++kt) {
            f32x4 xa = *(const f32x4*)(xn + kt * 32);
            f32x4 xb = *(const f32x4*)(xn + kt * 32 + 4);
            bf16x8 f;
            #pragma unroll
            for (int j = 0; j < 4; ++j) { f[j] = (bf16_t)xa[j]; f[4 + j] = (bf16_t)xb[j]; }
            xnf[kt] = f;
        }
        f32x4 wxacc[4];
        #pragma unroll
        for (int c = 0; c < 4; ++c) wxacc[c] = (f32x4){bPv[c], bPv[c], bPv[c], bPv[c]};
        #pragma unroll
        for (int kt = 0; kt < 4; ++kt)
            #pragma unroll
            for (int c = 0; c < 4; ++c)
                wxacc[c] = __builtin_amdgcn_mfma_f32_16x16x32_bf16(xf[kt], Wf[c * 4 + kt], wxacc[c], 0, 0, 0);
        for (int k = 0; k < K; ++k) {
            f32x4 acc[4];
            #pragma unroll
            for (int c = 0; c < 4; ++c) acc[c] = wxacc[c];
            const bf16_t* sbase = &S[p][m * SSTR];
            #pragma unroll
            for (int kt = 0; kt < 8; ++kt) {
                bf16x8 af = *(const bf16x8*)(sbase + kt * 32 + quad * 8);
                #pragma unroll
                for (int c = 0; c < 4; ++c)
                    acc[c] = __builtin_amdgcn_mfma_f32_16x16x32_bf16(af, Ef[c * 8 + kt], acc[c], 0, 0, 0);
            }
            bool last = (k == K - 1);
            #pragma unroll
            for (int c = 0; c < 4; ++c) {
                int col = colbase + c * 16;
                #pragma unroll
                for (int r = 0; r < 4; ++r) {
                    int e = c * 4 + r;
                    int row = quad * 4 + r;
                    float pre = acc[c][r] + sreg[e];
                    float T = fast_tanh(pre);
                    float hn = a * (T - hp[e]) + one_ma * hc[e];
                    float sn;
                    if (last) { hp[e] = hn; hc[e] = hn; sn = 2.0f * hn; }
                    else      { hc[e] = hn; sn = hn + hp[e]; }
                    sreg[e] = sn;
                    S[p ^ 1][row * SSTR + col] = (bf16_t)sn;
                }
            }
            p ^= 1;
            __syncthreads();
        }
        #pragma unroll
        for (int kt = 0; kt < 4; ++kt) xf[kt] = xnf[kt];
    }
    #pragma unroll
    for (int c = 0; c < 4; ++c)
        #pragma unroll
        for (int r = 0; r < 4; ++r) {
            int row = quad * 4 + r, col = colbase + c * 16;
            out[(g * 16 + row) * HID + col] = hp[c * 4 + r];
        }
}

extern "C" void kernel_launch(void* const* d_in, const int* in_sizes, int n_in,
                              void* d_out, int out_size, void* d_ws, size_t ws_size,
                              hipStream_t stream) {
    const float* x     = (const float*)d_in[0];
    const float* h     = (const float*)d_in[1];
    const float* W     = (const float*)d_in[2];
    const float* b     = (const float*)d_in[3];
    const float* V     = (const float*)d_in[4];
    const float* V2    = (const float*)d_in[5];
    const float* alpha = (const float*)d_in[6];
    const int*   Kp    = (const int*)d_in[7];

    char* ws = (char*)d_ws;
    float*  P   = (float*)ws;                    // 256 KB
    bf16_t* E   = (bf16_t*)(ws + (256u << 10));  // 128 KB
    bf16_t* WP  = (bf16_t*)(ws + (384u << 10));  // 64 KB
    float*  bP  = (float*)(ws + (448u << 10));   // 1 KB
    bf16_t* wxp = (bf16_t*)(ws + (512u << 10));  // 128 MB (optional)
    size_t need = (512u << 10) + (size_t)SEQ * 16 * 512 * 8 * sizeof(bf16_t);

    hipLaunchKernelGGL(k_P,  dim3(256), dim3(256), 0, stream, V2, V, P);
    hipLaunchKernelGGL(k_E,  dim3(256), dim3(256), 0, stream, P, E);
    hipLaunchKernelGGL(k_WP, dim3(129), dim3(256), 0, stream, W, b, P, WP, bP);
    if (ws_size >= need) {
        hipLaunchKernelGGL(k_wxp, dim3(2048), dim3(256), 0, stream, x, WP, bP, wxp);
        hipLaunchKernelGGL(k_scan_pre, dim3(16), dim3(512), 0, stream, h, alpha, Kp, E, wxp, (float*)d_out);
    } else {
        hipLaunchKernelGGL(k_scan_fused, dim3(16), dim3(256), 0, stream, h, alpha, Kp, E, WP, bP, x, (float*)d_out);
    }
}